// Round 11
// baseline (76.043 us; speedup 1.0000x reference)
//
#include <hip/hip_runtime.h>
#include <math.h>

// Problem constants
#define BB 32
#define TT 4096
#define DD 512
#define SS 256
#define SEG 128           // wave-segments per batch (each wave: 32 rows)
#define GRP 16            // groups of 2 rows per wave
static constexpr float INV_SCALE = 10.0f;   // 1/0.1

// ---------------------------------------------------------------------------
// Kernel 1: q = silu(t_star*W1+b1) @ W2 + b2.
// grid = B*8 blocks (b, jg); block 512 = 64 outputs x 8 k-groups.
// ---------------------------------------------------------------------------
__global__ __launch_bounds__(512) void k_q(
    const float* __restrict__ t_star, const float* __restrict__ W1,
    const float* __restrict__ b1, const float* __restrict__ W2,
    const float* __restrict__ b2, float* __restrict__ q) {
  const int b   = blockIdx.x >> 3;
  const int jg  = blockIdx.x & 7;
  const int tid = threadIdx.x;
  const int di  = tid & 63;
  const int kg  = tid >> 6;
  __shared__ float h[DD];
  __shared__ float red[8][64];
  {
    float x = t_star[b] * W1[tid] + b1[tid];
    h[tid] = x / (1.0f + __expf(-x));     // silu
  }
  __syncthreads();
  const float* w = W2 + jg * 64 + di;
  float acc = 0.0f;
#pragma unroll 8
  for (int kk = 0; kk < 64; ++kk) {
    const int k = kg * 64 + kk;
    acc += h[k] * w[(size_t)k * DD];
  }
  red[kg][di] = acc;
  __syncthreads();
  if (tid < 64) {
    float s = 0.0f;
#pragma unroll
    for (int g = 0; g < 8; ++g) s += red[g][tid];
    q[b * DD + jg * 64 + tid] = s + b2[jg * 64 + tid];
  }
}

// ---------------------------------------------------------------------------
// Kernel 2: LDS-staged flash pooling — R7 skeleton (2-row groups, 3-slot
// ring, depth-2 prefetch, vmcnt(8) steady, 48 KB, 1024 blocks) with
// CONTIGUOUS-PER-WAVE streams: wave s owns rows [s*32, s*32+32), so each
// wave reads a sequential 64 KB span (DRAM row-buffer hits), instead of
// 4 KB chunks strided 512 KB apart.
// No __syncthreads, no cross-wave LDS sharing.
// ---------------------------------------------------------------------------
#define GLDS(gp, lp)                                                        \
  __builtin_amdgcn_global_load_lds(                                         \
      (const __attribute__((address_space(1))) void*)(gp),                  \
      (__attribute__((address_space(3))) void*)(lp), 16, 0, 0)

__global__ __launch_bounds__(256) void k_fused(
    const float* __restrict__ ctx, const float* __restrict__ q,
    const float* __restrict__ t_star, const float* __restrict__ t_ctx,
    float* __restrict__ part_pool,    // [B*SEG*DD]
    float* __restrict__ part_ms) {    // [B*SEG*2]  (m, l)
  __shared__ __align__(16) float lds[4][3][2 * DD];   // 48 KB: [wave][slot][2 rows]
  const int wid  = threadIdx.x >> 6;
  const int lane = threadIdx.x & 63;
  const int w    = blockIdx.x * 4 + wid;   // global wave id
  const int b    = w >> 7;                 // / SEG
  const int s    = w & 127;                // % SEG

  const float4* qp = (const float4*)(q + b * DD);
  const float4 q0 = qp[lane];
  const float4 q1 = qp[64 + lane];
  const float ts = t_star[b];
  // lane g (g<16) holds the time-bias pair for group g's rows (s*32+2g, +1)
  const float2 tc = *(const float2*)(t_ctx + b * TT + s * 32 + 2 * (lane & 15));
  const float tbx = -fabsf(ts - tc.x) * INV_SCALE;
  const float tby = -fabsf(ts - tc.y) * INV_SCALE;

  float m = -INFINITY, l = 0.0f;
  float4 p0 = {0, 0, 0, 0}, p1 = {0, 0, 0, 0};

  const float* cb = ctx + ((size_t)b * TT + s * 32) * DD;   // wave's 64 KB span

  // prologue: stage groups 0,1 into slots 0,1 (group g = rows 2g,2g+1)
#pragma unroll
  for (int g = 0; g < 2; ++g) {
    const float* gb = cb + (size_t)g * 2 * DD;
    float* sb = &lds[wid][g][0];
#pragma unroll
    for (int piece = 0; piece < 4; ++piece)
      GLDS(gb + piece * 256 + lane * 4, sb + piece * 256);
  }

#pragma unroll
  for (int g = 0; g < GRP; ++g) {
    if (g + 2 < GRP) {
      const float* gb = cb + (size_t)(g + 2) * 2 * DD;
      float* sb = &lds[wid][(g + 2) % 3][0];
#pragma unroll
      for (int piece = 0; piece < 4; ++piece)
        GLDS(gb + piece * 256 + lane * 4, sb + piece * 256);
      asm volatile("s_waitcnt vmcnt(8)" ::: "memory");   // group g resident
    } else if (g + 2 == GRP) {
      asm volatile("s_waitcnt vmcnt(4)" ::: "memory");
    } else {
      asm volatile("s_waitcnt vmcnt(0)" ::: "memory");
    }

    const float4* sf = (const float4*)&lds[wid][g % 3][0];
    const float4 x0 = sf[lane];        // row0 dims [lane*4 .. +3]
    const float4 x1 = sf[64 + lane];   // row0 dims [256+lane*4 ..]
    const float4 y0 = sf[128 + lane];  // row1
    const float4 y1 = sf[192 + lane];

    float s0 = x0.x * q0.x + x0.y * q0.y + x0.z * q0.z + x0.w * q0.w +
               x1.x * q1.x + x1.y * q1.y + x1.z * q1.z + x1.w * q1.w;
    float s1 = y0.x * q0.x + y0.y * q0.y + y0.z * q0.z + y0.w * q0.w +
               y1.x * q1.x + y1.y * q1.y + y1.z * q1.z + y1.w * q1.w;
#pragma unroll
    for (int off = 32; off > 0; off >>= 1) {
      s0 += __shfl_xor(s0, off);
      s1 += __shfl_xor(s1, off);
    }
    s0 += __shfl(tbx, g);
    s1 += __shfl(tby, g);

    const float gm = fmaxf(s0, s1);
    const float nm = fmaxf(m, gm);
    const float sc = __expf(m - nm);   // g==0: exp(-inf)=0, p=l=0 anyway
    m = nm;
    const float e0 = __expf(s0 - m);
    const float e1 = __expf(s1 - m);
    l = l * sc + e0 + e1;
    p0.x = p0.x * sc + e0 * x0.x + e1 * y0.x;
    p0.y = p0.y * sc + e0 * x0.y + e1 * y0.y;
    p0.z = p0.z * sc + e0 * x0.z + e1 * y0.z;
    p0.w = p0.w * sc + e0 * x0.w + e1 * y0.w;
    p1.x = p1.x * sc + e0 * x1.x + e1 * y1.x;
    p1.y = p1.y * sc + e0 * x1.y + e1 * y1.y;
    p1.z = p1.z * sc + e0 * x1.z + e1 * y1.z;
    p1.w = p1.w * sc + e0 * x1.w + e1 * y1.w;
  }

  float4* pp = (float4*)(part_pool + (size_t)w * DD);
  pp[lane] = p0;
  pp[64 + lane] = p1;
  if (lane == 0) {
    part_ms[w * 2 + 0] = m;
    part_ms[w * 2 + 1] = l;
  }
}

// ---------------------------------------------------------------------------
// Kernel 3: merge segment partials into normalized pool[b,:].
// grid = B*4 (b, dg); block 512 = 128 d x 4 chunk-groups. part_pool read ONCE.
// ---------------------------------------------------------------------------
__global__ __launch_bounds__(512) void k_merge(
    const float* __restrict__ part_pool, const float* __restrict__ part_ms,
    float* __restrict__ pool) {
  const int b   = blockIdx.x >> 2;
  const int dg  = blockIdx.x & 3;
  const int tid = threadIdx.x;
  const int lane = tid & 63;
  const int base = b * SEG;
  __shared__ float scl[SEG];
  __shared__ float red[4][128];

  // wave-parallel global (M, Z) over 128 segments (each wave redundantly)
  const float mA = part_ms[(base + lane) * 2 + 0];
  const float mB = part_ms[(base + 64 + lane) * 2 + 0];
  const float lA = part_ms[(base + lane) * 2 + 1];
  const float lB = part_ms[(base + 64 + lane) * 2 + 1];
  float M = fmaxf(mA, mB);
#pragma unroll
  for (int off = 32; off > 0; off >>= 1) M = fmaxf(M, __shfl_xor(M, off));
  float Z = __expf(mA - M) * lA + __expf(mB - M) * lB;
#pragma unroll
  for (int off = 32; off > 0; off >>= 1) Z += __shfl_xor(Z, off);
  const float invZ = 1.0f / Z;
  if (tid < SEG) scl[tid] = __expf(part_ms[(base + tid) * 2] - M);
  __syncthreads();

  const int dl = tid & 127;
  const int cg = tid >> 7;
  float acc = 0.0f;
#pragma unroll 8
  for (int i = 0; i < 32; ++i) {
    const int c = cg * 32 + i;
    acc += scl[c] * part_pool[((size_t)base + c) * DD + dg * 128 + dl];
  }
  red[cg][dl] = acc;
  __syncthreads();
  if (tid < 128)
    pool[b * DD + dg * 128 + tid] =
        (red[0][tid] + red[1][tid] + red[2][tid] + red[3][tid]) * invZ;
}

// ---------------------------------------------------------------------------
// Kernel 4: out = pool @ Wout + bout. grid = B*8 (b,jg); block 256 = 4kg x 64j.
// ---------------------------------------------------------------------------
__global__ __launch_bounds__(256) void k_out(
    const float* __restrict__ pool, const float* __restrict__ Wout,
    const float* __restrict__ bout, float* __restrict__ out) {
  const int b   = blockIdx.x >> 3;
  const int jg  = blockIdx.x & 7;
  const int tid = threadIdx.x;
  const int kg  = tid >> 6;
  const int j   = tid & 63;
  const int jc  = jg * 64 + j;
  __shared__ float p[DD];
  __shared__ float red[4][64];

  p[tid] = pool[b * DD + tid];
  p[tid + 256] = pool[b * DD + 256 + tid];
  __syncthreads();

  float acc = 0.0f;
#pragma unroll 8
  for (int kk = 0; kk < 128; ++kk) {
    const int k = kg * 128 + kk;
    acc += p[k] * Wout[(size_t)k * DD + jc];
  }
  red[kg][j] = acc;
  __syncthreads();
  if (tid < 64) {
    const int jj = jg * 64 + tid;
    float o = red[0][tid] + red[1][tid] + red[2][tid] + red[3][tid] + bout[jj];
    if (jj < SS) out[b * SS + jj] = o;                       // mu
    else         out[BB * SS + b * SS + (jj - SS)] = o;      // log_sigma
  }
}

// ---------------------------------------------------------------------------
extern "C" void kernel_launch(void* const* d_in, const int* in_sizes, int n_in,
                              void* d_out, int out_size, void* d_ws, size_t ws_size,
                              hipStream_t stream) {
  const float* ctx    = (const float*)d_in[0];   // (B,T,D)
  const float* t_star = (const float*)d_in[1];   // (B,)
  const float* t_ctx  = (const float*)d_in[2];   // (B,T,1)
  const float* W1     = (const float*)d_in[3];   // (1,D)
  const float* b1     = (const float*)d_in[4];   // (D,)
  const float* W2     = (const float*)d_in[5];   // (D,D)
  const float* b2     = (const float*)d_in[6];   // (D,)
  const float* Wout   = (const float*)d_in[7];   // (D,2S)
  const float* bout   = (const float*)d_in[8];   // (2S,)
  float* out = (float*)d_out;

  float* ws = (float*)d_ws;
  float* q         = ws;                                   // B*D
  float* part_pool = q + (size_t)BB * DD;                  // B*SEG*D  (8 MB)
  float* part_ms   = part_pool + (size_t)BB * SEG * DD;    // B*SEG*2
  float* pool      = part_ms + (size_t)BB * SEG * 2;       // B*D

  k_q<<<BB * 8, 512, 0, stream>>>(t_star, W1, b1, W2, b2, q);
  k_fused<<<BB * SEG / 4, 256, 0, stream>>>(ctx, q, t_star, t_ctx, part_pool, part_ms);
  k_merge<<<BB * 4, 512, 0, stream>>>(part_pool, part_ms, pool);
  k_out<<<BB * 8, 256, 0, stream>>>(pool, Wout, bout, out);
}

// Round 12
// 66.446 us; speedup vs baseline: 1.1444x; 1.1444x over previous
//
#include <hip/hip_runtime.h>
#include <math.h>

// Problem constants
#define BB 32
#define TT 4096
#define DD 512
#define SS 256
#define SEG 128           // wave-segments per batch (each wave: 32 rows)
#define GRP 16            // groups of 2 rows per wave (GRP*2*SEG == TT)
static constexpr float INV_SCALE = 10.0f;   // 1/0.1

// ---------------------------------------------------------------------------
// Kernel 1: q = silu(t_star*W1+b1) @ W2 + b2.
// grid = B*8 blocks (b, jg); block 512 = 64 outputs x 8 k-groups.
// ---------------------------------------------------------------------------
__global__ __launch_bounds__(512) void k_q(
    const float* __restrict__ t_star, const float* __restrict__ W1,
    const float* __restrict__ b1, const float* __restrict__ W2,
    const float* __restrict__ b2, float* __restrict__ q) {
  const int b   = blockIdx.x >> 3;
  const int jg  = blockIdx.x & 7;
  const int tid = threadIdx.x;
  const int di  = tid & 63;
  const int kg  = tid >> 6;
  __shared__ float h[DD];
  __shared__ float red[8][64];
  {
    float x = t_star[b] * W1[tid] + b1[tid];
    h[tid] = x / (1.0f + __expf(-x));     // silu
  }
  __syncthreads();
  const float* w = W2 + jg * 64 + di;
  float acc = 0.0f;
#pragma unroll 8
  for (int kk = 0; kk < 64; ++kk) {
    const int k = kg * 64 + kk;
    acc += h[k] * w[(size_t)k * DD];
  }
  red[kg][di] = acc;
  __syncthreads();
  if (tid < 64) {
    float s = 0.0f;
#pragma unroll
    for (int g = 0; g < 8; ++g) s += red[g][tid];
    q[b * DD + jg * 64 + tid] = s + b2[jg * 64 + tid];
  }
}

// ---------------------------------------------------------------------------
// Kernel 2: LDS-staged flash pooling — R7 skeleton EXACTLY (2-row groups,
// 3-slot ring, depth-2 prefetch, vmcnt(8) steady, 48 KB, 1024 blocks,
// strided row mapping r = 2*(g*SEG+s)) with ONE change: NT cache policy
// (aux=2) on global_load_lds — ctx is a single-use 268 MB stream; evict-first
// in L2 avoids thrashing the 4 MB per-XCD L2 on the miss path.
// No __syncthreads, no cross-wave LDS sharing.
// ---------------------------------------------------------------------------
#define GLDS(gp, lp)                                                        \
  __builtin_amdgcn_global_load_lds(                                         \
      (const __attribute__((address_space(1))) void*)(gp),                  \
      (__attribute__((address_space(3))) void*)(lp), 16, 0, 2 /*NT*/)

__global__ __launch_bounds__(256) void k_fused(
    const float* __restrict__ ctx, const float* __restrict__ q,
    const float* __restrict__ t_star, const float* __restrict__ t_ctx,
    float* __restrict__ part_pool,    // [B*SEG*DD]
    float* __restrict__ part_ms) {    // [B*SEG*2]  (m, l)
  __shared__ __align__(16) float lds[4][3][2 * DD];   // 48 KB: [wave][slot][2 rows]
  const int wid  = threadIdx.x >> 6;
  const int lane = threadIdx.x & 63;
  const int w    = blockIdx.x * 4 + wid;   // global wave id
  const int b    = w >> 7;                 // / SEG
  const int s    = w & 127;                // % SEG

  const float4* qp = (const float4*)(q + b * DD);
  const float4 q0 = qp[lane];
  const float4 q1 = qp[64 + lane];
  const float ts = t_star[b];
  // lane g (g<16) holds the time-bias pair for its group's rows
  const float2 tc = *(const float2*)(t_ctx + b * TT + ((lane & 15) * 2 * SEG + 2 * s));
  const float tbx = -fabsf(ts - tc.x) * INV_SCALE;
  const float tby = -fabsf(ts - tc.y) * INV_SCALE;

  float m = -INFINITY, l = 0.0f;
  float4 p0 = {0, 0, 0, 0}, p1 = {0, 0, 0, 0};

  const float* cb = ctx + ((size_t)b * TT + 2 * s) * DD;   // group-0 base

  // prologue: stage groups 0,1 into slots 0,1
#pragma unroll
  for (int g = 0; g < 2; ++g) {
    const float* gb = cb + (size_t)g * 2 * SEG * DD;
    float* sb = &lds[wid][g][0];
#pragma unroll
    for (int piece = 0; piece < 4; ++piece)
      GLDS(gb + piece * 256 + lane * 4, sb + piece * 256);
  }

#pragma unroll
  for (int g = 0; g < GRP; ++g) {
    if (g + 2 < GRP) {
      const float* gb = cb + (size_t)(g + 2) * 2 * SEG * DD;
      float* sb = &lds[wid][(g + 2) % 3][0];
#pragma unroll
      for (int piece = 0; piece < 4; ++piece)
        GLDS(gb + piece * 256 + lane * 4, sb + piece * 256);
      asm volatile("s_waitcnt vmcnt(8)" ::: "memory");   // group g resident
    } else if (g + 2 == GRP) {
      asm volatile("s_waitcnt vmcnt(4)" ::: "memory");
    } else {
      asm volatile("s_waitcnt vmcnt(0)" ::: "memory");
    }

    const float4* sf = (const float4*)&lds[wid][g % 3][0];
    const float4 x0 = sf[lane];        // row0 dims [lane*4 .. +3]
    const float4 x1 = sf[64 + lane];   // row0 dims [256+lane*4 ..]
    const float4 y0 = sf[128 + lane];  // row1
    const float4 y1 = sf[192 + lane];

    float s0 = x0.x * q0.x + x0.y * q0.y + x0.z * q0.z + x0.w * q0.w +
               x1.x * q1.x + x1.y * q1.y + x1.z * q1.z + x1.w * q1.w;
    float s1 = y0.x * q0.x + y0.y * q0.y + y0.z * q0.z + y0.w * q0.w +
               y1.x * q1.x + y1.y * q1.y + y1.z * q1.z + y1.w * q1.w;
#pragma unroll
    for (int off = 32; off > 0; off >>= 1) {
      s0 += __shfl_xor(s0, off);
      s1 += __shfl_xor(s1, off);
    }
    s0 += __shfl(tbx, g);
    s1 += __shfl(tby, g);

    const float gm = fmaxf(s0, s1);
    const float nm = fmaxf(m, gm);
    const float sc = __expf(m - nm);   // g==0: exp(-inf)=0, p=l=0 anyway
    m = nm;
    const float e0 = __expf(s0 - m);
    const float e1 = __expf(s1 - m);
    l = l * sc + e0 + e1;
    p0.x = p0.x * sc + e0 * x0.x + e1 * y0.x;
    p0.y = p0.y * sc + e0 * x0.y + e1 * y0.y;
    p0.z = p0.z * sc + e0 * x0.z + e1 * y0.z;
    p0.w = p0.w * sc + e0 * x0.w + e1 * y0.w;
    p1.x = p1.x * sc + e0 * x1.x + e1 * y1.x;
    p1.y = p1.y * sc + e0 * x1.y + e1 * y1.y;
    p1.z = p1.z * sc + e0 * x1.z + e1 * y1.z;
    p1.w = p1.w * sc + e0 * x1.w + e1 * y1.w;
  }

  float4* pp = (float4*)(part_pool + (size_t)w * DD);
  pp[lane] = p0;
  pp[64 + lane] = p1;
  if (lane == 0) {
    part_ms[w * 2 + 0] = m;
    part_ms[w * 2 + 1] = l;
  }
}

// ---------------------------------------------------------------------------
// Kernel 3: merge segment partials into normalized pool[b,:].
// grid = B*4 (b, dg); block 512 = 128 d x 4 chunk-groups. part_pool read ONCE.
// ---------------------------------------------------------------------------
__global__ __launch_bounds__(512) void k_merge(
    const float* __restrict__ part_pool, const float* __restrict__ part_ms,
    float* __restrict__ pool) {
  const int b   = blockIdx.x >> 2;
  const int dg  = blockIdx.x & 3;
  const int tid = threadIdx.x;
  const int lane = tid & 63;
  const int base = b * SEG;
  __shared__ float scl[SEG];
  __shared__ float red[4][128];

  // wave-parallel global (M, Z) over 128 segments (each wave redundantly)
  const float mA = part_ms[(base + lane) * 2 + 0];
  const float mB = part_ms[(base + 64 + lane) * 2 + 0];
  const float lA = part_ms[(base + lane) * 2 + 1];
  const float lB = part_ms[(base + 64 + lane) * 2 + 1];
  float M = fmaxf(mA, mB);
#pragma unroll
  for (int off = 32; off > 0; off >>= 1) M = fmaxf(M, __shfl_xor(M, off));
  float Z = __expf(mA - M) * lA + __expf(mB - M) * lB;
#pragma unroll
  for (int off = 32; off > 0; off >>= 1) Z += __shfl_xor(Z, off);
  const float invZ = 1.0f / Z;
  if (tid < SEG) scl[tid] = __expf(part_ms[(base + tid) * 2] - M);
  __syncthreads();

  const int dl = tid & 127;
  const int cg = tid >> 7;
  float acc = 0.0f;
#pragma unroll 8
  for (int i = 0; i < 32; ++i) {
    const int c = cg * 32 + i;
    acc += scl[c] * part_pool[((size_t)base + c) * DD + dg * 128 + dl];
  }
  red[cg][dl] = acc;
  __syncthreads();
  if (tid < 128)
    pool[b * DD + dg * 128 + tid] =
        (red[0][tid] + red[1][tid] + red[2][tid] + red[3][tid]) * invZ;
}

// ---------------------------------------------------------------------------
// Kernel 4: out = pool @ Wout + bout. grid = B*8 (b,jg); block 256 = 4kg x 64j.
// ---------------------------------------------------------------------------
__global__ __launch_bounds__(256) void k_out(
    const float* __restrict__ pool, const float* __restrict__ Wout,
    const float* __restrict__ bout, float* __restrict__ out) {
  const int b   = blockIdx.x >> 3;
  const int jg  = blockIdx.x & 7;
  const int tid = threadIdx.x;
  const int kg  = tid >> 6;
  const int j   = tid & 63;
  const int jc  = jg * 64 + j;
  __shared__ float p[DD];
  __shared__ float red[4][64];

  p[tid] = pool[b * DD + tid];
  p[tid + 256] = pool[b * DD + 256 + tid];
  __syncthreads();

  float acc = 0.0f;
#pragma unroll 8
  for (int kk = 0; kk < 128; ++kk) {
    const int k = kg * 128 + kk;
    acc += p[k] * Wout[(size_t)k * DD + jc];
  }
  red[kg][j] = acc;
  __syncthreads();
  if (tid < 64) {
    const int jj = jg * 64 + tid;
    float o = red[0][tid] + red[1][tid] + red[2][tid] + red[3][tid] + bout[jj];
    if (jj < SS) out[b * SS + jj] = o;                       // mu
    else         out[BB * SS + b * SS + (jj - SS)] = o;      // log_sigma
  }
}

// ---------------------------------------------------------------------------
extern "C" void kernel_launch(void* const* d_in, const int* in_sizes, int n_in,
                              void* d_out, int out_size, void* d_ws, size_t ws_size,
                              hipStream_t stream) {
  const float* ctx    = (const float*)d_in[0];   // (B,T,D)
  const float* t_star = (const float*)d_in[1];   // (B,)
  const float* t_ctx  = (const float*)d_in[2];   // (B,T,1)
  const float* W1     = (const float*)d_in[3];   // (1,D)
  const float* b1     = (const float*)d_in[4];   // (D,)
  const float* W2     = (const float*)d_in[5];   // (D,D)
  const float* b2     = (const float*)d_in[6];   // (D,)
  const float* Wout   = (const float*)d_in[7];   // (D,2S)
  const float* bout   = (const float*)d_in[8];   // (2S,)
  float* out = (float*)d_out;

  float* ws = (float*)d_ws;
  float* q         = ws;                                   // B*D
  float* part_pool = q + (size_t)BB * DD;                  // B*SEG*D  (8 MB)
  float* part_ms   = part_pool + (size_t)BB * SEG * DD;    // B*SEG*2
  float* pool      = part_ms + (size_t)BB * SEG * 2;       // B*D

  k_q<<<BB * 8, 512, 0, stream>>>(t_star, W1, b1, W2, b2, q);
  k_fused<<<BB * SEG / 4, 256, 0, stream>>>(ctx, q, t_star, t_ctx, part_pool, part_ms);
  k_merge<<<BB * 4, 512, 0, stream>>>(part_pool, part_ms, pool);
  k_out<<<BB * 8, 256, 0, stream>>>(pool, Wout, bout, out);
}

// Round 14
// 61.521 us; speedup vs baseline: 1.2360x; 1.0801x over previous
//
#include <hip/hip_runtime.h>
#include <math.h>

// Problem constants
#define BB 32
#define TT 4096
#define DD 512
#define SS 256
#define WPB 96            // waves per batch (96*32 batches = 3072 waves total)
#define NBLK 768          // 768 blocks * 4 waves = 3072; 3 blocks/CU, all resident
static constexpr float INV_SCALE = 10.0f;   // 1/0.1

typedef float f32x4 __attribute__((ext_vector_type(4)));   // for NT stores

// ---------------------------------------------------------------------------
// Kernel 1: q = silu(t_star*W1+b1) @ W2 + b2.
// ---------------------------------------------------------------------------
__global__ __launch_bounds__(512) void k_q(
    const float* __restrict__ t_star, const float* __restrict__ W1,
    const float* __restrict__ b1, const float* __restrict__ W2,
    const float* __restrict__ b2, float* __restrict__ q) {
  const int b   = blockIdx.x >> 3;
  const int jg  = blockIdx.x & 7;
  const int tid = threadIdx.x;
  const int di  = tid & 63;
  const int kg  = tid >> 6;
  __shared__ float h[DD];
  __shared__ float red[8][64];
  {
    float x = t_star[b] * W1[tid] + b1[tid];
    h[tid] = x / (1.0f + __expf(-x));     // silu
  }
  __syncthreads();
  const float* w = W2 + jg * 64 + di;
  float acc = 0.0f;
#pragma unroll 8
  for (int kk = 0; kk < 64; ++kk) {
    const int k = kg * 64 + kk;
    acc += h[k] * w[(size_t)k * DD];
  }
  red[kg][di] = acc;
  __syncthreads();
  if (tid < 64) {
    float s = 0.0f;
#pragma unroll
    for (int g = 0; g < 8; ++g) s += red[g][tid];
    q[b * DD + jg * 64 + tid] = s + b2[jg * 64 + tid];
  }
}

// ---------------------------------------------------------------------------
// Kernel 2: LDS-staged flash pooling — persistent balanced grid.
// 768 blocks (= 3/CU at 48 KB, ALL resident) x 4 waves = 3072 waves.
// Batch b owns waves [96b, 96b+96); wave v<32 gets 22 two-row groups,
// v>=32 gets 21 (2048 groups/batch, max imbalance 3%). Group g of wave v
// covers rows {2*(g*96+v), +1} (strided coherent front, as R7/R12).
// Inner loop identical to R12: 3-slot ring, depth-2 prefetch, NT aux,
// vmcnt(8) steady. No __syncthreads, no cross-wave LDS sharing.
// ---------------------------------------------------------------------------
#define GLDS(gp, lp)                                                        \
  __builtin_amdgcn_global_load_lds(                                         \
      (const __attribute__((address_space(1))) void*)(gp),                  \
      (__attribute__((address_space(3))) void*)(lp), 16, 0, 2 /*NT*/)

__global__ __launch_bounds__(256) void k_fused(
    const float* __restrict__ ctx, const float* __restrict__ q,
    const float* __restrict__ t_star, const float* __restrict__ t_ctx,
    float* __restrict__ part_pool,    // [B*WPB*DD]
    float* __restrict__ part_ms) {    // [B*WPB*2]  (m, l)
  __shared__ __align__(16) float lds[4][3][2 * DD];   // 48 KB
  const int wid  = threadIdx.x >> 6;
  const int lane = threadIdx.x & 63;
  const int W    = blockIdx.x * 4 + wid;   // global wave id, 0..3071
  const int b    = W / WPB;                // batch
  const int v    = W % WPB;                // wave-in-batch, 0..95
  const int NG   = (v < 32) ? 22 : 21;     // groups for this wave

  const float4* qp = (const float4*)(q + b * DD);
  const float4 q0 = qp[lane];
  const float4 q1 = qp[64 + lane];
  const float ts = t_star[b];

  // lane g (g < NG) holds the time-bias pair for its step's rows
  const int lg = lane & 31;
  int gidx = lg * WPB + v;
  if (gidx >= TT / 2) gidx = v;            // clamp unused lanes in-bounds
  const float2 tc = *(const float2*)(t_ctx + b * TT + 2 * gidx);
  const float tbx = -fabsf(ts - tc.x) * INV_SCALE;
  const float tby = -fabsf(ts - tc.y) * INV_SCALE;

  float m = -INFINITY, l = 0.0f;
  float4 p0 = {0, 0, 0, 0}, p1 = {0, 0, 0, 0};

  const float* cbatch = ctx + (size_t)b * TT * DD;

  // prologue: stage groups 0,1 into slots 0,1 (every wave has NG >= 21)
#pragma unroll
  for (int g = 0; g < 2; ++g) {
    const float* gb = cbatch + (size_t)(g * WPB + v) * 2 * DD;
    float* sb = &lds[wid][g][0];
#pragma unroll
    for (int piece = 0; piece < 4; ++piece)
      GLDS(gb + piece * 256 + lane * 4, sb + piece * 256);
  }

  int rs = 0, wslot = 2;                   // read slot, write slot (mod-3 ring)
  for (int g = 0; g < NG; ++g) {
    if (g + 2 < NG) {
      const float* gb = cbatch + (size_t)((g + 2) * WPB + v) * 2 * DD;
      float* sb = &lds[wid][wslot][0];
#pragma unroll
      for (int piece = 0; piece < 4; ++piece)
        GLDS(gb + piece * 256 + lane * 4, sb + piece * 256);
      asm volatile("s_waitcnt vmcnt(8)" ::: "memory");   // group g resident
    } else if (g + 2 == NG) {
      asm volatile("s_waitcnt vmcnt(4)" ::: "memory");
    } else {
      asm volatile("s_waitcnt vmcnt(0)" ::: "memory");
    }

    const float4* sf = (const float4*)&lds[wid][rs][0];
    const float4 x0 = sf[lane];        // row0 dims [lane*4 .. +3]
    const float4 x1 = sf[64 + lane];   // row0 dims [256+lane*4 ..]
    const float4 y0 = sf[128 + lane];  // row1
    const float4 y1 = sf[192 + lane];

    float s0 = x0.x * q0.x + x0.y * q0.y + x0.z * q0.z + x0.w * q0.w +
               x1.x * q1.x + x1.y * q1.y + x1.z * q1.z + x1.w * q1.w;
    float s1 = y0.x * q0.x + y0.y * q0.y + y0.z * q0.z + y0.w * q0.w +
               y1.x * q1.x + y1.y * q1.y + y1.z * q1.z + y1.w * q1.w;
#pragma unroll
    for (int off = 32; off > 0; off >>= 1) {
      s0 += __shfl_xor(s0, off);
      s1 += __shfl_xor(s1, off);
    }
    s0 += __shfl(tbx, g);
    s1 += __shfl(tby, g);

    const float gm = fmaxf(s0, s1);
    const float nm = fmaxf(m, gm);
    const float sc = __expf(m - nm);   // g==0: exp(-inf)=0, p=l=0 anyway
    m = nm;
    const float e0 = __expf(s0 - m);
    const float e1 = __expf(s1 - m);
    l = l * sc + e0 + e1;
    p0.x = p0.x * sc + e0 * x0.x + e1 * y0.x;
    p0.y = p0.y * sc + e0 * x0.y + e1 * y0.y;
    p0.z = p0.z * sc + e0 * x0.z + e1 * y0.z;
    p0.w = p0.w * sc + e0 * x0.w + e1 * y0.w;
    p1.x = p1.x * sc + e0 * x1.x + e1 * y1.x;
    p1.y = p1.y * sc + e0 * x1.y + e1 * y1.y;
    p1.z = p1.z * sc + e0 * x1.z + e1 * y1.z;
    p1.w = p1.w * sc + e0 * x1.w + e1 * y1.w;

    rs = (rs == 2) ? 0 : rs + 1;
    wslot = (wslot == 2) ? 0 : wslot + 1;
  }

  // NT store of partials (single-use stream, consumed by k_merge)
  f32x4* pp = (f32x4*)(part_pool + (size_t)W * DD);
  f32x4 v0 = {p0.x, p0.y, p0.z, p0.w};
  f32x4 v1 = {p1.x, p1.y, p1.z, p1.w};
  __builtin_nontemporal_store(v0, pp + lane);
  __builtin_nontemporal_store(v1, pp + 64 + lane);
  if (lane == 0) {
    part_ms[W * 2 + 0] = m;
    part_ms[W * 2 + 1] = l;
  }
}

// ---------------------------------------------------------------------------
// Kernel 3: merge 96 wave-partials per batch into normalized pool[b,:].
// grid = B*4 (b, dg); block 512 = 128 d x 4 chunk-groups (24 chunks each).
// ---------------------------------------------------------------------------
__global__ __launch_bounds__(512) void k_merge(
    const float* __restrict__ part_pool, const float* __restrict__ part_ms,
    float* __restrict__ pool) {
  const int b   = blockIdx.x >> 2;
  const int dg  = blockIdx.x & 3;
  const int tid = threadIdx.x;
  const int lane = tid & 63;
  const int base = b * WPB;
  __shared__ float scl[WPB];
  __shared__ float red[4][128];

  // wave-parallel global (M, Z) over 96 partials (each wave redundantly)
  const float mA = part_ms[(base + lane) * 2 + 0];
  const float lA = part_ms[(base + lane) * 2 + 1];
  float mB = -INFINITY, lB = 0.0f;
  if (lane < WPB - 64) {
    mB = part_ms[(base + 64 + lane) * 2 + 0];
    lB = part_ms[(base + 64 + lane) * 2 + 1];
  }
  float M = fmaxf(mA, mB);
#pragma unroll
  for (int off = 32; off > 0; off >>= 1) M = fmaxf(M, __shfl_xor(M, off));
  float Z = __expf(mA - M) * lA + ((lane < WPB - 64) ? __expf(mB - M) * lB : 0.0f);
#pragma unroll
  for (int off = 32; off > 0; off >>= 1) Z += __shfl_xor(Z, off);
  const float invZ = 1.0f / Z;
  if (tid < WPB) scl[tid] = __expf(part_ms[(base + tid) * 2] - M);
  __syncthreads();

  const int dl = tid & 127;
  const int cg = tid >> 7;
  float acc = 0.0f;
#pragma unroll 8
  for (int i = 0; i < 24; ++i) {
    const int c = cg * 24 + i;
    acc += scl[c] * part_pool[((size_t)base + c) * DD + dg * 128 + dl];
  }
  red[cg][dl] = acc;
  __syncthreads();
  if (tid < 128)
    pool[b * DD + dg * 128 + tid] =
        (red[0][tid] + red[1][tid] + red[2][tid] + red[3][tid]) * invZ;
}

// ---------------------------------------------------------------------------
// Kernel 4: out = pool @ Wout + bout. grid = B*8 (b,jg); block 256 = 4kg x 64j.
// (bid&7 == jg -> each XCD sees one jg column-slab -> Wout L2-resident)
// ---------------------------------------------------------------------------
__global__ __launch_bounds__(256) void k_out(
    const float* __restrict__ pool, const float* __restrict__ Wout,
    const float* __restrict__ bout, float* __restrict__ out) {
  const int b   = blockIdx.x >> 3;
  const int jg  = blockIdx.x & 7;
  const int tid = threadIdx.x;
  const int kg  = tid >> 6;
  const int j   = tid & 63;
  const int jc  = jg * 64 + j;
  __shared__ float p[DD];
  __shared__ float red[4][64];

  p[tid] = pool[b * DD + tid];
  p[tid + 256] = pool[b * DD + 256 + tid];
  __syncthreads();

  float acc = 0.0f;
#pragma unroll 8
  for (int kk = 0; kk < 128; ++kk) {
    const int k = kg * 128 + kk;
    acc += p[k] * Wout[(size_t)k * DD + jc];
  }
  red[kg][j] = acc;
  __syncthreads();
  if (tid < 64) {
    const int jj = jg * 64 + tid;
    float o = red[0][tid] + red[1][tid] + red[2][tid] + red[3][tid] + bout[jj];
    if (jj < SS) out[b * SS + jj] = o;                       // mu
    else         out[BB * SS + b * SS + (jj - SS)] = o;      // log_sigma
  }
}

// ---------------------------------------------------------------------------
extern "C" void kernel_launch(void* const* d_in, const int* in_sizes, int n_in,
                              void* d_out, int out_size, void* d_ws, size_t ws_size,
                              hipStream_t stream) {
  const float* ctx    = (const float*)d_in[0];   // (B,T,D)
  const float* t_star = (const float*)d_in[1];   // (B,)
  const float* t_ctx  = (const float*)d_in[2];   // (B,T,1)
  const float* W1     = (const float*)d_in[3];   // (1,D)
  const float* b1     = (const float*)d_in[4];   // (D,)
  const float* W2     = (const float*)d_in[5];   // (D,D)
  const float* b2     = (const float*)d_in[6];   // (D,)
  const float* Wout   = (const float*)d_in[7];   // (D,2S)
  const float* bout   = (const float*)d_in[8];   // (2S,)
  float* out = (float*)d_out;

  float* ws = (float*)d_ws;
  float* q         = ws;                                   // B*D
  float* part_pool = q + (size_t)BB * DD;                  // B*WPB*D (6.3 MB)
  float* part_ms   = part_pool + (size_t)BB * WPB * DD;    // B*WPB*2
  float* pool      = part_ms + (size_t)BB * WPB * 2;       // B*D

  k_q<<<BB * 8, 512, 0, stream>>>(t_star, W1, b1, W2, b2, q);
  k_fused<<<NBLK, 256, 0, stream>>>(ctx, q, t_star, t_ctx, part_pool, part_ms);
  k_merge<<<BB * 4, 512, 0, stream>>>(part_pool, part_ms, pool);
  k_out<<<BB * 8, 256, 0, stream>>>(pool, Wout, bout, out);
}